// Round 1
// baseline (266.999 us; speedup 1.0000x reference)
//
#include <hip/hip_runtime.h>

typedef _Float16 half8  __attribute__((ext_vector_type(8)));
typedef _Float16 half4v __attribute__((ext_vector_type(4)));
typedef float    floatx4 __attribute__((ext_vector_type(4)));

#define K_DIM 2312
#define N_DIM 1024
#define M_DIM 16384
#define T_DIM 16
#define B_DIM 1024
#define O_DIM 10
#define NT 73               // ceil(2312/32)
#define LDP 40              // padded LDS leading dim (halfs)

// ---------------- GEMM1: h[M,N] = x[M,K] @ W1[N,K]^T + b1 ----------------
// 128x128 tile, BK=32, 256 threads (4 waves, 2x2), fp32->fp16 convert in staging.

__device__ __forceinline__ void stage_load(const float* __restrict__ x,
                                           const float* __restrict__ w,
                                           int m0, int n0, int k0, int tid,
                                           floatx4 (&ar)[4], floatx4 (&br)[4]) {
  int r = tid >> 3;
  int c = (tid & 7) * 4;
  bool ok = (k0 + c) < K_DIM;     // float4-granular: K_DIM % 4 == 0
  #pragma unroll
  for (int i = 0; i < 4; ++i) {
    int row = r + 32 * i;
    if (ok) {
      ar[i] = *(const floatx4*)(x + (size_t)(m0 + row) * K_DIM + k0 + c);
      br[i] = *(const floatx4*)(w + (size_t)(n0 + row) * K_DIM + k0 + c);
    } else {
      ar[i] = floatx4{0.f, 0.f, 0.f, 0.f};
      br[i] = floatx4{0.f, 0.f, 0.f, 0.f};
    }
  }
}

__device__ __forceinline__ void stage_write(_Float16* __restrict__ Ab,
                                            _Float16* __restrict__ Bb, int tid,
                                            const floatx4 (&ar)[4], const floatx4 (&br)[4]) {
  int r = tid >> 3;
  int c = (tid & 7) * 4;
  #pragma unroll
  for (int i = 0; i < 4; ++i) {
    int row = r + 32 * i;
    half4v av, bv;
    #pragma unroll
    for (int e = 0; e < 4; ++e) {
      av[e] = (_Float16)ar[i][e];   // RTN converts for accuracy
      bv[e] = (_Float16)br[i][e];
    }
    *(half4v*)(Ab + row * LDP + c) = av;
    *(half4v*)(Bb + row * LDP + c) = bv;
  }
}

__global__ __launch_bounds__(256) void gemm1_kernel(const float* __restrict__ x,
                                                    const float* __restrict__ W1,
                                                    const float* __restrict__ b1,
                                                    float* __restrict__ h) {
  __shared__ _Float16 Al[2][128 * LDP];
  __shared__ _Float16 Bl[2][128 * LDP];

  int tid  = threadIdx.x;
  int lane = tid & 63;
  int w    = tid >> 6;
  int wm   = (w >> 1) * 64;
  int wn   = (w & 1) * 64;
  int bm   = blockIdx.x >> 3;   // bn = bid&7 -> each XCD owns one bn column (W1 panel L2-resident)
  int bn   = blockIdx.x & 7;
  int m0   = bm * 128;
  int n0   = bn * 128;

  floatx4 acc[4][4];
  #pragma unroll
  for (int i = 0; i < 4; ++i)
    #pragma unroll
    for (int j = 0; j < 4; ++j)
      acc[i][j] = floatx4{0.f, 0.f, 0.f, 0.f};

  floatx4 ar[4], br[4];
  stage_load(x, W1, m0, n0, 0, tid, ar, br);
  stage_write(Al[0], Bl[0], tid, ar, br);
  __syncthreads();

  int fr = lane & 15;          // fragment row/col index
  int kc = (lane >> 4) * 8;    // k-chunk (8 contiguous halfs)

  int cur = 0;
  for (int kt = 0; kt < NT; ++kt) {
    if (kt + 1 < NT) stage_load(x, W1, m0, n0, (kt + 1) * 32, tid, ar, br);

    const _Float16* Ab = Al[cur];
    const _Float16* Bb = Bl[cur];
    half8 af[4], bf[4];
    #pragma unroll
    for (int f = 0; f < 4; ++f) {
      af[f] = *(const half8*)(Ab + (wm + f * 16 + fr) * LDP + kc);
      bf[f] = *(const half8*)(Bb + (wn + f * 16 + fr) * LDP + kc);
    }
    #pragma unroll
    for (int i = 0; i < 4; ++i)
      #pragma unroll
      for (int j = 0; j < 4; ++j)
        acc[i][j] = __builtin_amdgcn_mfma_f32_16x16x32_f16(af[i], bf[j], acc[i][j], 0, 0, 0);

    if (kt + 1 < NT) stage_write(Al[cur ^ 1], Bl[cur ^ 1], tid, ar, br);
    __syncthreads();
    cur ^= 1;
  }

  // epilogue: C/D layout col = lane&15, row = (lane>>4)*4 + reg  [m89/m91-verified]
  int cr = (lane >> 4) * 4;
  #pragma unroll
  for (int j = 0; j < 4; ++j) {
    int col = n0 + wn + j * 16 + fr;
    float bv = b1[col];
    #pragma unroll
    for (int i = 0; i < 4; ++i) {
      int rbase = m0 + wm + i * 16 + cr;
      #pragma unroll
      for (int e = 0; e < 4; ++e)
        h[(size_t)(rbase + e) * N_DIM + col] = acc[i][j][e] + bv;
    }
  }
}

// ---------------- Phase B: temporal LIF chain, one wave per batch row ----------------

__global__ __launch_bounds__(256) void snn_temporal_kernel(const float* __restrict__ h,
                                                           const float* __restrict__ W2,
                                                           const float* __restrict__ b2,
                                                           float* __restrict__ out) {
  __shared__ float w2s[O_DIM * N_DIM];   // 40 KB
  int tid = threadIdx.x;
  for (int i = tid; i < O_DIM * N_DIM; i += 256) w2s[i] = W2[i];
  __syncthreads();

  int wave = tid >> 6;
  int lane = tid & 63;
  int b = blockIdx.x * 4 + wave;
  const float* hrow = h + (size_t)b * (T_DIM * N_DIM);
  float* orow = out + (size_t)b * (T_DIM * O_DIM);

  float v1[16];
  #pragma unroll
  for (int e = 0; e < 16; ++e) v1[e] = 0.f;
  float v2 = 0.f;
  float bias2 = (lane < O_DIM) ? b2[lane] : 0.f;

  // prefetch t=0
  floatx4 hv[4];
  #pragma unroll
  for (int c = 0; c < 4; ++c) hv[c] = *(const floatx4*)(hrow + c * 256 + lane * 4);

  for (int t = 0; t < T_DIM; ++t) {
    floatx4 hn[4];
    if (t + 1 < T_DIM) {
      #pragma unroll
      for (int c = 0; c < 4; ++c)
        hn[c] = *(const floatx4*)(hrow + (t + 1) * N_DIM + c * 256 + lane * 4);
    }

    // LIF layer 1 (16 hidden units per lane)
    float sarr[16];
    #pragma unroll
    for (int c = 0; c < 4; ++c) {
      #pragma unroll
      for (int e = 0; e < 4; ++e) {
        int ii = c * 4 + e;
        float vn = 0.9f * v1[ii] + hv[c][e];
        float s  = 1.f / (1.f + __expf(10.f - 10.f * vn));
        v1[ii] = vn * (1.f - s);
        sarr[ii] = s;
      }
    }

    // o = s1 @ W2^T   (partial per lane, then wave butterfly reduce)
    float part[10];
    #pragma unroll
    for (int o = 0; o < O_DIM; ++o) {
      float a = 0.f;
      #pragma unroll
      for (int c = 0; c < 4; ++c) {
        floatx4 w4 = *(const floatx4*)&w2s[o * N_DIM + c * 256 + lane * 4];
        a += sarr[c * 4 + 0] * w4[0] + sarr[c * 4 + 1] * w4[1]
           + sarr[c * 4 + 2] * w4[2] + sarr[c * 4 + 3] * w4[3];
      }
      part[o] = a;
    }
    #pragma unroll
    for (int m = 1; m < 64; m <<= 1) {
      #pragma unroll
      for (int o = 0; o < O_DIM; ++o) part[o] += __shfl_xor(part[o], m, 64);
    }

    // static-index selection of part[lane] (avoid scratch: rule #20)
    float po = part[0];
    #pragma unroll
    for (int o = 1; o < O_DIM; ++o) po = (lane == o) ? part[o] : po;

    if (lane < O_DIM) {
      float vo = 0.9f * v2 + po + bias2;
      float s2 = 1.f / (1.f + __expf(10.f - 10.f * vo));
      v2 = vo * (1.f - s2);
      orow[t * O_DIM + lane] = s2;
    }

    #pragma unroll
    for (int c = 0; c < 4; ++c) hv[c] = hn[c];
  }
}

extern "C" void kernel_launch(void* const* d_in, const int* in_sizes, int n_in,
                              void* d_out, int out_size, void* d_ws, size_t ws_size,
                              hipStream_t stream) {
  const float* x  = (const float*)d_in[0];
  const float* W1 = (const float*)d_in[1];
  const float* b1 = (const float*)d_in[2];
  const float* W2 = (const float*)d_in[3];
  const float* b2 = (const float*)d_in[4];
  float* out = (float*)d_out;
  float* h   = (float*)d_ws;   // 16384*1024*4 = 64 MiB scratch for h_all

  gemm1_kernel<<<dim3(1024), dim3(256), 0, stream>>>(x, W1, b1, h);
  snn_temporal_kernel<<<dim3(256), dim3(256), 0, stream>>>(h, W2, b2, out);
}

// Round 2
// 216.692 us; speedup vs baseline: 1.2322x; 1.2322x over previous
//
#include <hip/hip_runtime.h>

typedef _Float16 half8  __attribute__((ext_vector_type(8)));
typedef _Float16 half4v __attribute__((ext_vector_type(4)));
typedef float    floatx4 __attribute__((ext_vector_type(4)));

#define K_DIM 2312
#define KP    2368          // K padded to multiple of 32 (74 * 32)
#define N_DIM 1024
#define M_DIM 16384
#define T_DIM 16
#define B_DIM 1024
#define O_DIM 10
#define NKT   74            // KP / 32
#define NT_OLD 73           // ceil(2312/32) for fallback path
#define LDP 40              // fallback LDS pad

// =====================================================================
// Fast path A: fp32 -> fp16 convert + zero-pad K to 2368
// one block per row; 296 half8-chunks per row (289 real, 7 pad)
// =====================================================================
__global__ __launch_bounds__(256) void cvt_f32_f16_pad(const float* __restrict__ src,
                                                       _Float16* __restrict__ dst) {
  int row = blockIdx.x;
  const float* s = src + (size_t)row * K_DIM;
  _Float16* d = dst + (size_t)row * KP;
  for (int c = threadIdx.x; c < 296; c += 256) {
    half8 o;
    if (c < 289) {
      floatx4 a = *(const floatx4*)(s + c * 8);
      floatx4 b = *(const floatx4*)(s + c * 8 + 4);
      #pragma unroll
      for (int e = 0; e < 4; ++e) { o[e] = (_Float16)a[e]; o[4 + e] = (_Float16)b[e]; }
    } else {
      o = half8{0, 0, 0, 0, 0, 0, 0, 0};
    }
    *(half8*)(d + c * 8) = o;
  }
}

// =====================================================================
// Fast path B: h[M,N] = xh[M,KP] @ w1h[N,KP]^T + b1
// m97 structure: 128x128 tile, BK=32, 4 waves (2x2), global_load_lds,
// both-sides XOR swizzle (slot = chunk ^ ((row>>1)&3)) for even banks.
// =====================================================================
__device__ __forceinline__ void gload16(const _Float16* g, _Float16* l) {
  __builtin_amdgcn_global_load_lds((const __attribute__((address_space(1))) void*)g,
                                   (__attribute__((address_space(3))) void*)l, 16, 0, 0);
}

__global__ __launch_bounds__(256) void gemm_f16_kernel(const _Float16* __restrict__ A,
                                                       const _Float16* __restrict__ Bw,
                                                       const float* __restrict__ b1,
                                                       float* __restrict__ h) {
  __shared__ __align__(16) _Float16 Al[2][128 * 32];
  __shared__ __align__(16) _Float16 Bl[2][128 * 32];

  const int tid  = threadIdx.x;
  const int lane = tid & 63;
  const int w    = tid >> 6;
  const int bm   = blockIdx.x >> 3;   // bn = bid&7 -> one bn column per XCD (W1 panel L2-resident)
  const int bn   = blockIdx.x & 7;
  const int m0   = bm * 128;
  const int n0   = bn * 128;
  const int wm   = (w >> 1) * 64;
  const int wn   = (w & 1) * 64;

  // ---- staging geometry: wave w stages rows [w*32, w*32+32) of both tiles ----
  const int rl  = lane >> 2;                 // row within 16-row group
  const int swz = (lane >> 3) & 3;           // == ((row_local)>>1)&3 for staged rows
  const int cch = (lane & 3) ^ swz;          // inverse-swizzled global k-chunk
  const _Float16* ag = A  + (size_t)(m0 + w * 32 + rl) * KP + cch * 8;
  const _Float16* bg = Bw + (size_t)(n0 + w * 32 + rl) * KP + cch * 8;
  const int labase = (w * 32) * 32;          // LDS base (halfs), wave-uniform

  floatx4 acc[4][4];
  #pragma unroll
  for (int i = 0; i < 4; ++i)
    #pragma unroll
    for (int j = 0; j < 4; ++j)
      acc[i][j] = floatx4{0.f, 0.f, 0.f, 0.f};

  // prologue: stage tile 0 into buf 0
  {
    gload16(ag,           &Al[0][labase]);
    gload16(ag + 16 * KP, &Al[0][labase + 16 * 32]);
    gload16(bg,           &Bl[0][labase]);
    gload16(bg + 16 * KP, &Bl[0][labase + 16 * 32]);
  }
  __syncthreads();

  const int fr = lane & 15;
  const int g  = lane >> 4;
  const int rdslot = (g ^ ((fr >> 1) & 3)) * 8;   // swizzled 16B slot (halfs)

  int cur = 0;
  for (int kt = 0; kt < NKT; ++kt) {
    if (kt + 1 < NKT) {
      const int k0 = (kt + 1) * 32;
      _Float16* la = &Al[cur ^ 1][labase];
      _Float16* lb = &Bl[cur ^ 1][labase];
      gload16(ag + k0,           la);
      gload16(ag + 16 * KP + k0, la + 16 * 32);
      gload16(bg + k0,           lb);
      gload16(bg + 16 * KP + k0, lb + 16 * 32);
    }

    const _Float16* Ab = Al[cur];
    const _Float16* Bb = Bl[cur];
    half8 af[4], bf[4];
    #pragma unroll
    for (int f = 0; f < 4; ++f) {
      af[f] = *(const half8*)(Ab + (wm + f * 16 + fr) * 32 + rdslot);
      bf[f] = *(const half8*)(Bb + (wn + f * 16 + fr) * 32 + rdslot);
    }
    #pragma unroll
    for (int i = 0; i < 4; ++i)
      #pragma unroll
      for (int j = 0; j < 4; ++j)
        acc[i][j] = __builtin_amdgcn_mfma_f32_16x16x32_f16(af[i], bf[j], acc[i][j], 0, 0, 0);

    __syncthreads();
    cur ^= 1;
  }

  // epilogue: C/D layout col = lane&15, row = (lane>>4)*4 + reg
  const int cr = (lane >> 4) * 4;
  #pragma unroll
  for (int j = 0; j < 4; ++j) {
    int col = n0 + wn + j * 16 + fr;
    float bv = b1[col];
    #pragma unroll
    for (int i = 0; i < 4; ++i) {
      int rbase = m0 + wm + i * 16 + cr;
      #pragma unroll
      for (int e = 0; e < 4; ++e)
        h[(size_t)(rbase + e) * N_DIM + col] = acc[i][j][e] + bv;
    }
  }
}

// =====================================================================
// Fallback path (R1): reg-staged fp32->fp16 GEMM, used if ws too small
// =====================================================================
__device__ __forceinline__ void stage_load(const float* __restrict__ x,
                                           const float* __restrict__ w,
                                           int m0, int n0, int k0, int tid,
                                           floatx4 (&ar)[4], floatx4 (&br)[4]) {
  int r = tid >> 3;
  int c = (tid & 7) * 4;
  bool ok = (k0 + c) < K_DIM;
  #pragma unroll
  for (int i = 0; i < 4; ++i) {
    int row = r + 32 * i;
    if (ok) {
      ar[i] = *(const floatx4*)(x + (size_t)(m0 + row) * K_DIM + k0 + c);
      br[i] = *(const floatx4*)(w + (size_t)(n0 + row) * K_DIM + k0 + c);
    } else {
      ar[i] = floatx4{0.f, 0.f, 0.f, 0.f};
      br[i] = floatx4{0.f, 0.f, 0.f, 0.f};
    }
  }
}

__device__ __forceinline__ void stage_write(_Float16* __restrict__ Ab,
                                            _Float16* __restrict__ Bb, int tid,
                                            const floatx4 (&ar)[4], const floatx4 (&br)[4]) {
  int r = tid >> 3;
  int c = (tid & 7) * 4;
  #pragma unroll
  for (int i = 0; i < 4; ++i) {
    int row = r + 32 * i;
    half4v av, bv;
    #pragma unroll
    for (int e = 0; e < 4; ++e) {
      av[e] = (_Float16)ar[i][e];
      bv[e] = (_Float16)br[i][e];
    }
    *(half4v*)(Ab + row * LDP + c) = av;
    *(half4v*)(Bb + row * LDP + c) = bv;
  }
}

__global__ __launch_bounds__(256) void gemm1_kernel(const float* __restrict__ x,
                                                    const float* __restrict__ W1,
                                                    const float* __restrict__ b1,
                                                    float* __restrict__ h) {
  __shared__ _Float16 Al[2][128 * LDP];
  __shared__ _Float16 Bl[2][128 * LDP];

  int tid  = threadIdx.x;
  int lane = tid & 63;
  int w    = tid >> 6;
  int wm   = (w >> 1) * 64;
  int wn   = (w & 1) * 64;
  int m0   = (blockIdx.x >> 3) * 128;
  int n0   = (blockIdx.x & 7) * 128;

  floatx4 acc[4][4];
  #pragma unroll
  for (int i = 0; i < 4; ++i)
    #pragma unroll
    for (int j = 0; j < 4; ++j)
      acc[i][j] = floatx4{0.f, 0.f, 0.f, 0.f};

  floatx4 ar[4], br[4];
  stage_load(x, W1, m0, n0, 0, tid, ar, br);
  stage_write(Al[0], Bl[0], tid, ar, br);
  __syncthreads();

  int fr = lane & 15;
  int kc = (lane >> 4) * 8;

  int cur = 0;
  for (int kt = 0; kt < NT_OLD; ++kt) {
    if (kt + 1 < NT_OLD) stage_load(x, W1, m0, n0, (kt + 1) * 32, tid, ar, br);

    const _Float16* Ab = Al[cur];
    const _Float16* Bb = Bl[cur];
    half8 af[4], bf[4];
    #pragma unroll
    for (int f = 0; f < 4; ++f) {
      af[f] = *(const half8*)(Ab + (wm + f * 16 + fr) * LDP + kc);
      bf[f] = *(const half8*)(Bb + (wn + f * 16 + fr) * LDP + kc);
    }
    #pragma unroll
    for (int i = 0; i < 4; ++i)
      #pragma unroll
      for (int j = 0; j < 4; ++j)
        acc[i][j] = __builtin_amdgcn_mfma_f32_16x16x32_f16(af[i], bf[j], acc[i][j], 0, 0, 0);

    if (kt + 1 < NT_OLD) stage_write(Al[cur ^ 1], Bl[cur ^ 1], tid, ar, br);
    __syncthreads();
    cur ^= 1;
  }

  int cr = (lane >> 4) * 4;
  #pragma unroll
  for (int j = 0; j < 4; ++j) {
    int col = n0 + wn + j * 16 + fr;
    float bv = b1[col];
    #pragma unroll
    for (int i = 0; i < 4; ++i) {
      int rbase = m0 + wm + i * 16 + cr;
      #pragma unroll
      for (int e = 0; e < 4; ++e)
        h[(size_t)(rbase + e) * N_DIM + col] = acc[i][j][e] + bv;
    }
  }
}

// =====================================================================
// Phase C: temporal LIF chain, one wave per batch row
// =====================================================================
__global__ __launch_bounds__(256) void snn_temporal_kernel(const float* __restrict__ h,
                                                           const float* __restrict__ W2,
                                                           const float* __restrict__ b2,
                                                           float* __restrict__ out) {
  __shared__ float w2s[O_DIM * N_DIM];   // 40 KB
  int tid = threadIdx.x;
  for (int i = tid; i < O_DIM * N_DIM; i += 256) w2s[i] = W2[i];
  __syncthreads();

  int wave = tid >> 6;
  int lane = tid & 63;
  int b = blockIdx.x * 4 + wave;
  const float* hrow = h + (size_t)b * (T_DIM * N_DIM);
  float* orow = out + (size_t)b * (T_DIM * O_DIM);

  float v1[16];
  #pragma unroll
  for (int e = 0; e < 16; ++e) v1[e] = 0.f;
  float v2 = 0.f;
  float bias2 = (lane < O_DIM) ? b2[lane] : 0.f;

  floatx4 hv[4];
  #pragma unroll
  for (int c = 0; c < 4; ++c) hv[c] = *(const floatx4*)(hrow + c * 256 + lane * 4);

  for (int t = 0; t < T_DIM; ++t) {
    floatx4 hn[4];
    if (t + 1 < T_DIM) {
      #pragma unroll
      for (int c = 0; c < 4; ++c)
        hn[c] = *(const floatx4*)(hrow + (t + 1) * N_DIM + c * 256 + lane * 4);
    }

    float sarr[16];
    #pragma unroll
    for (int c = 0; c < 4; ++c) {
      #pragma unroll
      for (int e = 0; e < 4; ++e) {
        int ii = c * 4 + e;
        float vn = 0.9f * v1[ii] + hv[c][e];
        float s  = 1.f / (1.f + __expf(10.f - 10.f * vn));
        v1[ii] = vn * (1.f - s);
        sarr[ii] = s;
      }
    }

    float part[10];
    #pragma unroll
    for (int o = 0; o < O_DIM; ++o) {
      float a = 0.f;
      #pragma unroll
      for (int c = 0; c < 4; ++c) {
        floatx4 w4 = *(const floatx4*)&w2s[o * N_DIM + c * 256 + lane * 4];
        a += sarr[c * 4 + 0] * w4[0] + sarr[c * 4 + 1] * w4[1]
           + sarr[c * 4 + 2] * w4[2] + sarr[c * 4 + 3] * w4[3];
      }
      part[o] = a;
    }
    #pragma unroll
    for (int m = 1; m < 64; m <<= 1) {
      #pragma unroll
      for (int o = 0; o < O_DIM; ++o) part[o] += __shfl_xor(part[o], m, 64);
    }

    float po = part[0];
    #pragma unroll
    for (int o = 1; o < O_DIM; ++o) po = (lane == o) ? part[o] : po;

    if (lane < O_DIM) {
      float vo = 0.9f * v2 + po + bias2;
      float s2 = 1.f / (1.f + __expf(10.f - 10.f * vo));
      v2 = vo * (1.f - s2);
      orow[t * O_DIM + lane] = s2;
    }

    #pragma unroll
    for (int c = 0; c < 4; ++c) hv[c] = hn[c];
  }
}

extern "C" void kernel_launch(void* const* d_in, const int* in_sizes, int n_in,
                              void* d_out, int out_size, void* d_ws, size_t ws_size,
                              hipStream_t stream) {
  const float* x  = (const float*)d_in[0];
  const float* W1 = (const float*)d_in[1];
  const float* b1 = (const float*)d_in[2];
  const float* W2 = (const float*)d_in[3];
  const float* b2 = (const float*)d_in[4];
  float* out = (float*)d_out;

  float* h = (float*)d_ws;  // 64 MiB

  const size_t H_BYTES  = (size_t)M_DIM * N_DIM * 4;            // 67,108,864
  const size_t XH_BYTES = (size_t)M_DIM * KP * 2;               // 77,594,624
  const size_t WH_BYTES = (size_t)N_DIM * KP * 2;               //  4,849,664
  const size_t NEED = H_BYTES + XH_BYTES + WH_BYTES;            // 149,553,152

  if (ws_size >= NEED) {
    _Float16* xh  = (_Float16*)((char*)d_ws + H_BYTES);
    _Float16* w1h = (_Float16*)((char*)d_ws + H_BYTES + XH_BYTES);
    cvt_f32_f16_pad<<<dim3(M_DIM), dim3(256), 0, stream>>>(x, xh);
    cvt_f32_f16_pad<<<dim3(N_DIM), dim3(256), 0, stream>>>(W1, w1h);
    gemm_f16_kernel<<<dim3(1024), dim3(256), 0, stream>>>(xh, w1h, b1, h);
  } else {
    gemm1_kernel<<<dim3(1024), dim3(256), 0, stream>>>(x, W1, b1, h);
  }
  snn_temporal_kernel<<<dim3(256), dim3(256), 0, stream>>>(h, W2, b2, out);
}

// Round 3
// 172.572 us; speedup vs baseline: 1.5472x; 1.2557x over previous
//
#include <hip/hip_runtime.h>

typedef _Float16 half8  __attribute__((ext_vector_type(8)));
typedef _Float16 half4v __attribute__((ext_vector_type(4)));
typedef float    floatx4 __attribute__((ext_vector_type(4)));

#define K_DIM 2312
#define KP    2368          // K padded to multiple of 32 (74 * 32)
#define N_DIM 1024
#define M_DIM 16384
#define T_DIM 16
#define B_DIM 1024
#define O_DIM 10
#define NKT   74            // KP / 32
#define NT_OLD 73
#define LDP 40

// =====================================================================
// cvt: fp32 -> fp16 with K zero-pad to 2368
// =====================================================================
__global__ __launch_bounds__(256) void cvt_f32_f16_pad(const float* __restrict__ src,
                                                       _Float16* __restrict__ dst) {
  int row = blockIdx.x;
  const float* s = src + (size_t)row * K_DIM;
  _Float16* d = dst + (size_t)row * KP;
  for (int c = threadIdx.x; c < 296; c += 256) {
    half8 o;
    if (c < 289) {
      floatx4 a = *(const floatx4*)(s + c * 8);
      floatx4 b = *(const floatx4*)(s + c * 8 + 4);
      #pragma unroll
      for (int e = 0; e < 4; ++e) { o[e] = (_Float16)a[e]; o[4 + e] = (_Float16)b[e]; }
    } else {
      o = half8{0, 0, 0, 0, 0, 0, 0, 0};
    }
    *(half8*)(d + c * 8) = o;
  }
}

// =====================================================================
// GEMM: h[M,N] = xh[M,KP] @ w1h[N,KP]^T + b1
// 256x256 tile, BK=32, 512 threads (8 waves 2x4), 4-slot LDS ring,
// 3-tile prefetch, counted vmcnt(8) (T4), raw s_barrier (no drain).
// =====================================================================
__device__ __forceinline__ void gload16(const _Float16* g, _Float16* l) {
  __builtin_amdgcn_global_load_lds((const __attribute__((address_space(1))) void*)g,
                                   (__attribute__((address_space(3))) void*)l, 16, 0, 0);
}

__global__ __launch_bounds__(512, 2) void gemm_f16_256(const _Float16* __restrict__ A,
                                                       const _Float16* __restrict__ Bw,
                                                       const float* __restrict__ b1,
                                                       float* __restrict__ h) {
  __shared__ __align__(16) _Float16 As[4][256 * 32];   // 64 KiB
  __shared__ __align__(16) _Float16 Bs[4][256 * 32];   // 64 KiB

  const int tid  = threadIdx.x;
  const int lane = tid & 63;
  const int w    = tid >> 6;          // 0..7
  const int wm   = (w >> 2) * 128;    // 2 row-waves
  const int wn   = (w & 3) * 64;      // 4 col-waves
  const int bm   = blockIdx.x & 63;   // same-bm blocks land on same XCD (bid%8 preserved mod 64)
  const int bn   = blockIdx.x >> 6;
  const int m0   = bm * 256;
  const int n0   = bn * 256;

  // ---- staging geometry: wave w stages rows [w*32, w*32+32) of A and B ----
  const int rlo = lane >> 2;                 // 0..15 within 16-row group
  const int key = (rlo >> 1) & 3;            // swizzle key = (row mod 16)>>1 & 3
  const int cch = (lane & 3) ^ key;          // inverse-swizzled global k-chunk
  const _Float16* ag = A  + (size_t)(m0 + w * 32 + rlo) * KP + cch * 8;
  const _Float16* bg = Bw + (size_t)(n0 + w * 32 + rlo) * KP + cch * 8;
  const int ldsbase = (w * 32) * 32;         // wave-uniform LDS base (halfs)

  floatx4 acc[8][4];
  #pragma unroll
  for (int i = 0; i < 8; ++i)
    #pragma unroll
    for (int j = 0; j < 4; ++j)
      acc[i][j] = floatx4{0.f, 0.f, 0.f, 0.f};

  // ---- fragment read offsets (constant across iters; slot varies) ----
  const int fr  = lane & 15;
  const int g   = lane >> 4;
  const int rds = (g ^ ((fr >> 1) & 3)) * 8;  // swizzled 16B slot (halfs)
  int offA[8], offB[4];
  #pragma unroll
  for (int i = 0; i < 8; ++i) offA[i] = (wm + i * 16 + fr) * 32 + rds;
  #pragma unroll
  for (int j = 0; j < 4; ++j) offB[j] = (wn + j * 16 + fr) * 32 + rds;

  // ---- prologue: stage tiles 0,1,2 into slots 0,1,2 (12 loads/thread) ----
  #pragma unroll
  for (int t = 0; t < 3; ++t) {
    gload16(ag + t * 32,            &As[t][ldsbase]);
    gload16(ag + t * 32 + 16 * KP,  &As[t][ldsbase + 16 * 32]);
    gload16(bg + t * 32,            &Bs[t][ldsbase]);
    gload16(bg + t * 32 + 16 * KP,  &Bs[t][ldsbase + 16 * 32]);
  }
  asm volatile("s_waitcnt vmcnt(8)" ::: "memory");   // tile 0 landed
  __builtin_amdgcn_s_barrier();                      // publish tile 0

  auto compute_tile = [&](int sb) {
    half8 af[8], bf[4];
    #pragma unroll
    for (int i = 0; i < 8; ++i) af[i] = *(const half8*)(&As[sb][offA[i]]);
    #pragma unroll
    for (int j = 0; j < 4; ++j) bf[j] = *(const half8*)(&Bs[sb][offB[j]]);
    __builtin_amdgcn_s_setprio(1);
    #pragma unroll
    for (int i = 0; i < 8; ++i)
      #pragma unroll
      for (int j = 0; j < 4; ++j)
        acc[i][j] = __builtin_amdgcn_mfma_f32_16x16x32_f16(af[i], bf[j], acc[i][j], 0, 0, 0);
    __builtin_amdgcn_s_setprio(0);
    asm volatile("s_waitcnt lgkmcnt(0)" ::: "memory");  // reads done before slot reuse
    __builtin_amdgcn_s_barrier();                       // end-of-tile (publish + anti-dep)
  };

  // ---- main loop: stage kt+3, wait vmcnt(8) (retires kt+1), compute kt ----
  for (int kt = 0; kt < NKT - 3; ++kt) {
    const int ts = kt + 3;
    const int sb = ts & 3;               // == (kt-1)&3: freed by last iter's barrier
    gload16(ag + ts * 32,           &As[sb][ldsbase]);
    gload16(ag + ts * 32 + 16 * KP, &As[sb][ldsbase + 16 * 32]);
    gload16(bg + ts * 32,           &Bs[sb][ldsbase]);
    gload16(bg + ts * 32 + 16 * KP, &Bs[sb][ldsbase + 16 * 32]);
    asm volatile("s_waitcnt vmcnt(8)" ::: "memory");
    compute_tile(kt & 3);
  }
  // tail: tiles NKT-3, NKT-2, NKT-1 (no more staging)
  asm volatile("s_waitcnt vmcnt(4)" ::: "memory");
  compute_tile((NKT - 3) & 3);
  asm volatile("s_waitcnt vmcnt(0)" ::: "memory");
  compute_tile((NKT - 2) & 3);
  compute_tile((NKT - 1) & 3);

  // ---- epilogue: C/D layout col = lane&15, row = (lane>>4)*4 + reg ----
  const int cr = (lane >> 4) * 4;
  #pragma unroll
  for (int j = 0; j < 4; ++j) {
    int col = n0 + wn + j * 16 + fr;
    float bv = b1[col];
    #pragma unroll
    for (int i = 0; i < 8; ++i) {
      int rbase = m0 + wm + i * 16 + cr;
      #pragma unroll
      for (int e = 0; e < 4; ++e)
        h[(size_t)(rbase + e) * N_DIM + col] = acc[i][j][e] + bv;
    }
  }
}

// =====================================================================
// Fallback (R1): reg-staged fp32->fp16 GEMM, used only if ws too small
// =====================================================================
__device__ __forceinline__ void stage_load(const float* __restrict__ x,
                                           const float* __restrict__ w,
                                           int m0, int n0, int k0, int tid,
                                           floatx4 (&ar)[4], floatx4 (&br)[4]) {
  int r = tid >> 3;
  int c = (tid & 7) * 4;
  bool ok = (k0 + c) < K_DIM;
  #pragma unroll
  for (int i = 0; i < 4; ++i) {
    int row = r + 32 * i;
    if (ok) {
      ar[i] = *(const floatx4*)(x + (size_t)(m0 + row) * K_DIM + k0 + c);
      br[i] = *(const floatx4*)(w + (size_t)(n0 + row) * K_DIM + k0 + c);
    } else {
      ar[i] = floatx4{0.f, 0.f, 0.f, 0.f};
      br[i] = floatx4{0.f, 0.f, 0.f, 0.f};
    }
  }
}

__device__ __forceinline__ void stage_write(_Float16* __restrict__ Ab,
                                            _Float16* __restrict__ Bb, int tid,
                                            const floatx4 (&ar)[4], const floatx4 (&br)[4]) {
  int r = tid >> 3;
  int c = (tid & 7) * 4;
  #pragma unroll
  for (int i = 0; i < 4; ++i) {
    int row = r + 32 * i;
    half4v av, bv;
    #pragma unroll
    for (int e = 0; e < 4; ++e) {
      av[e] = (_Float16)ar[i][e];
      bv[e] = (_Float16)br[i][e];
    }
    *(half4v*)(Ab + row * LDP + c) = av;
    *(half4v*)(Bb + row * LDP + c) = bv;
  }
}

__global__ __launch_bounds__(256) void gemm1_kernel(const float* __restrict__ x,
                                                    const float* __restrict__ W1,
                                                    const float* __restrict__ b1,
                                                    float* __restrict__ h) {
  __shared__ _Float16 Al[2][128 * LDP];
  __shared__ _Float16 Bl[2][128 * LDP];

  int tid  = threadIdx.x;
  int lane = tid & 63;
  int w    = tid >> 6;
  int wm   = (w >> 1) * 64;
  int wn   = (w & 1) * 64;
  int m0   = (blockIdx.x >> 3) * 128;
  int n0   = (blockIdx.x & 7) * 128;

  floatx4 acc[4][4];
  #pragma unroll
  for (int i = 0; i < 4; ++i)
    #pragma unroll
    for (int j = 0; j < 4; ++j)
      acc[i][j] = floatx4{0.f, 0.f, 0.f, 0.f};

  floatx4 ar[4], br[4];
  stage_load(x, W1, m0, n0, 0, tid, ar, br);
  stage_write(Al[0], Bl[0], tid, ar, br);
  __syncthreads();

  int fr = lane & 15;
  int kc = (lane >> 4) * 8;

  int cur = 0;
  for (int kt = 0; kt < NT_OLD; ++kt) {
    if (kt + 1 < NT_OLD) stage_load(x, W1, m0, n0, (kt + 1) * 32, tid, ar, br);

    const _Float16* Ab = Al[cur];
    const _Float16* Bb = Bl[cur];
    half8 af[4], bf[4];
    #pragma unroll
    for (int f = 0; f < 4; ++f) {
      af[f] = *(const half8*)(Ab + (wm + f * 16 + fr) * LDP + kc);
      bf[f] = *(const half8*)(Bb + (wn + f * 16 + fr) * LDP + kc);
    }
    #pragma unroll
    for (int i = 0; i < 4; ++i)
      #pragma unroll
      for (int j = 0; j < 4; ++j)
        acc[i][j] = __builtin_amdgcn_mfma_f32_16x16x32_f16(af[i], bf[j], acc[i][j], 0, 0, 0);

    if (kt + 1 < NT_OLD) stage_write(Al[cur ^ 1], Bl[cur ^ 1], tid, ar, br);
    __syncthreads();
    cur ^= 1;
  }

  int cr = (lane >> 4) * 4;
  #pragma unroll
  for (int j = 0; j < 4; ++j) {
    int col = n0 + wn + j * 16 + fr;
    float bv = b1[col];
    #pragma unroll
    for (int i = 0; i < 4; ++i) {
      int rbase = m0 + wm + i * 16 + cr;
      #pragma unroll
      for (int e = 0; e < 4; ++e)
        h[(size_t)(rbase + e) * N_DIM + col] = acc[i][j][e] + bv;
    }
  }
}

// =====================================================================
// temporal LIF chain, one wave per batch row
// =====================================================================
__global__ __launch_bounds__(256) void snn_temporal_kernel(const float* __restrict__ h,
                                                           const float* __restrict__ W2,
                                                           const float* __restrict__ b2,
                                                           float* __restrict__ out) {
  __shared__ float w2s[O_DIM * N_DIM];   // 40 KB
  int tid = threadIdx.x;
  for (int i = tid; i < O_DIM * N_DIM; i += 256) w2s[i] = W2[i];
  __syncthreads();

  int wave = tid >> 6;
  int lane = tid & 63;
  int b = blockIdx.x * 4 + wave;
  const float* hrow = h + (size_t)b * (T_DIM * N_DIM);
  float* orow = out + (size_t)b * (T_DIM * O_DIM);

  float v1[16];
  #pragma unroll
  for (int e = 0; e < 16; ++e) v1[e] = 0.f;
  float v2 = 0.f;
  float bias2 = (lane < O_DIM) ? b2[lane] : 0.f;

  floatx4 hv[4];
  #pragma unroll
  for (int c = 0; c < 4; ++c) hv[c] = *(const floatx4*)(hrow + c * 256 + lane * 4);

  for (int t = 0; t < T_DIM; ++t) {
    floatx4 hn[4];
    if (t + 1 < T_DIM) {
      #pragma unroll
      for (int c = 0; c < 4; ++c)
        hn[c] = *(const floatx4*)(hrow + (t + 1) * N_DIM + c * 256 + lane * 4);
    }

    float sarr[16];
    #pragma unroll
    for (int c = 0; c < 4; ++c) {
      #pragma unroll
      for (int e = 0; e < 4; ++e) {
        int ii = c * 4 + e;
        float vn = 0.9f * v1[ii] + hv[c][e];
        float s  = 1.f / (1.f + __expf(10.f - 10.f * vn));
        v1[ii] = vn * (1.f - s);
        sarr[ii] = s;
      }
    }

    float part[10];
    #pragma unroll
    for (int o = 0; o < O_DIM; ++o) {
      float a = 0.f;
      #pragma unroll
      for (int c = 0; c < 4; ++c) {
        floatx4 w4 = *(const floatx4*)&w2s[o * N_DIM + c * 256 + lane * 4];
        a += sarr[c * 4 + 0] * w4[0] + sarr[c * 4 + 1] * w4[1]
           + sarr[c * 4 + 2] * w4[2] + sarr[c * 4 + 3] * w4[3];
      }
      part[o] = a;
    }
    #pragma unroll
    for (int m = 1; m < 64; m <<= 1) {
      #pragma unroll
      for (int o = 0; o < O_DIM; ++o) part[o] += __shfl_xor(part[o], m, 64);
    }

    float po = part[0];
    #pragma unroll
    for (int o = 1; o < O_DIM; ++o) po = (lane == o) ? part[o] : po;

    if (lane < O_DIM) {
      float vo = 0.9f * v2 + po + bias2;
      float s2 = 1.f / (1.f + __expf(10.f - 10.f * vo));
      v2 = vo * (1.f - s2);
      orow[t * O_DIM + lane] = s2;
    }

    #pragma unroll
    for (int c = 0; c < 4; ++c) hv[c] = hn[c];
  }
}

extern "C" void kernel_launch(void* const* d_in, const int* in_sizes, int n_in,
                              void* d_out, int out_size, void* d_ws, size_t ws_size,
                              hipStream_t stream) {
  const float* x  = (const float*)d_in[0];
  const float* W1 = (const float*)d_in[1];
  const float* b1 = (const float*)d_in[2];
  const float* W2 = (const float*)d_in[3];
  const float* b2 = (const float*)d_in[4];
  float* out = (float*)d_out;

  float* h = (float*)d_ws;  // 64 MiB

  const size_t H_BYTES  = (size_t)M_DIM * N_DIM * 4;
  const size_t XH_BYTES = (size_t)M_DIM * KP * 2;
  const size_t WH_BYTES = (size_t)N_DIM * KP * 2;
  const size_t NEED = H_BYTES + XH_BYTES + WH_BYTES;

  if (ws_size >= NEED) {
    _Float16* xh  = (_Float16*)((char*)d_ws + H_BYTES);
    _Float16* w1h = (_Float16*)((char*)d_ws + H_BYTES + XH_BYTES);
    cvt_f32_f16_pad<<<dim3(M_DIM), dim3(256), 0, stream>>>(x, xh);
    cvt_f32_f16_pad<<<dim3(N_DIM), dim3(256), 0, stream>>>(W1, w1h);
    gemm_f16_256<<<dim3(256), dim3(512), 0, stream>>>(xh, w1h, b1, h);
  } else {
    gemm1_kernel<<<dim3(1024), dim3(256), 0, stream>>>(x, W1, b1, h);
  }
  snn_temporal_kernel<<<dim3(256), dim3(256), 0, stream>>>(h, W2, b2, out);
}